// Round 7
// baseline (388.118 us; speedup 1.0000x reference)
//
#include <hip/hip_runtime.h>
#include <hip/hip_bf16.h>

// TripletLoss N=8192, D=128. Round 7: two dispatches.
//   1) prep: fp32->bf16 cast + row squared-norms + zero completion counter
//   2) pairs_fused: 1024 blocks (normal launch, ~16 waves/CU), fused
//      GEMM+mining; the LAST block (threadfence + atomic counter) reduces the
//      partial array to the scalar. No grid.sync, no occupancy cap.
// Math: MFMA C init = -(x2i+x2j)/2 so acc = -d2/2; s = sqrt(max(-acc,5e-9)),
// dist = sqrt2*s; neg weight exp(-dist); pos weight exp(dist-30)
// (shift-stabilized; self-pair contributes e^-30 ~ 9e-14, excluded by the
// pl>1e-12 validity test). LDS B-tile is fragment-contiguous ([jt][kc][lane]
// x 16B) -> all ds ops lane-linear, zero bank conflicts (verified round 6).

typedef __bf16 bf16x8 __attribute__((ext_vector_type(8)));
typedef float f32x4 __attribute__((ext_vector_type(4)));

#define NROWS 8192
#define DIM 128
#define JSPLIT 16
#define JSPAN (NROWS / JSPLIT)     // 512
#define JTILE 128
#define NTILES (JSPAN / JTILE)     // 4
#define NBLK (64 * JSPLIT)         // 1024
#define MARGIN_F 0.3f
#define SQRT2_F 1.41421356f

// ---------------- dispatch 1: cast + norms + zero counter ----------------
__global__ __launch_bounds__(256) void prep_kernel(const float* __restrict__ F,
                                                   __hip_bfloat16* __restrict__ Fb,
                                                   float* __restrict__ x2,
                                                   int* __restrict__ counter) {
    const int tid = threadIdx.x;
    const int row = blockIdx.x * 16 + (tid >> 4);
    const int c8 = tid & 15;                     // 16 threads/row, 32B each
    const float4* src = (const float4*)(F + (size_t)row * DIM);
    float4 f0 = src[c8 * 2], f1 = src[c8 * 2 + 1];
    __hip_bfloat16* dst = Fb + (size_t)row * DIM + c8 * 8;
    ((__hip_bfloat162*)dst)[0] = __float22bfloat162_rn(make_float2(f0.x, f0.y));
    ((__hip_bfloat162*)dst)[1] = __float22bfloat162_rn(make_float2(f0.z, f0.w));
    ((__hip_bfloat162*)dst)[2] = __float22bfloat162_rn(make_float2(f1.x, f1.y));
    ((__hip_bfloat162*)dst)[3] = __float22bfloat162_rn(make_float2(f1.z, f1.w));
    float ss = f0.x * f0.x + f0.y * f0.y + f0.z * f0.z + f0.w * f0.w
             + f1.x * f1.x + f1.y * f1.y + f1.z * f1.z + f1.w * f1.w;
#pragma unroll
    for (int m = 8; m > 0; m >>= 1) ss += __shfl_xor(ss, m, 64);
    if (c8 == 0) x2[row] = ss;
    if (blockIdx.x == 0 && tid == 0) counter[0] = 0;
}

// ---------------- dispatch 2: fused GEMM + mining + last-block finalize ----
__global__ __launch_bounds__(256, 4) void pairs_kernel(
        const __hip_bfloat16* __restrict__ Fb,
        const float* __restrict__ x2,
        const int* __restrict__ labels,
        float4* __restrict__ partial,
        int* __restrict__ counter,
        float* __restrict__ out) {
    __shared__ bf16x8 sB[2048];          // 32 KB; chunk c = (jt*4+kc)*64 + lane
    __shared__ int sLab[JTILE];
    __shared__ float sX2h[JTILE];        // -0.5 * x2j
    __shared__ int sDone;
    __shared__ float rS[4], rC[4];

    const int tid = threadIdx.x;
    const int wave = tid >> 6, lane = tid & 63;
    const int quad = lane >> 4, lm = lane & 15;
    const int iblk = blockIdx.x;                 // 0..63
    const int jslice = blockIdx.y;               // 0..15
    const int wbase = iblk * 128 + wave * 32;    // this wave's 32 i-rows
    const int j0 = jslice * JSPAN;

    // A fragments: 2 row-groups x 4 K-chunks; A[m=lm][k=quad*8+j]
    bf16x8 a[2][4];
#pragma unroll
    for (int g = 0; g < 2; ++g)
#pragma unroll
        for (int kc = 0; kc < 4; ++kc)
            a[g][kc] = *(const bf16x8*)(Fb + (size_t)(wbase + g * 16 + lm) * DIM
                                        + kc * 32 + quad * 8);

    // C/D: col(n)=lm (j), row(m)=quad*4+r (i); idx = g*4+r
    float x2ih[8]; int labi[8];
#pragma unroll
    for (int g = 0; g < 2; ++g)
#pragma unroll
        for (int r = 0; r < 4; ++r) {
            int row = wbase + g * 16 + quad * 4 + r;
            x2ih[g * 4 + r] = -0.5f * x2[row];
            labi[g * 4 + r] = labels[row];
        }

    float nl[8], ns[8], pl[8], ps[8];
#pragma unroll
    for (int i = 0; i < 8; ++i) { nl[i] = 0.f; ns[i] = 0.f; pl[i] = 0.f; ps[i] = 0.f; }

    // staging map: chunk c = tid + s*256; jt=c>>8, kc=(c>>6)&3, c&63 = lane
    int srcoff[8];
#pragma unroll
    for (int s = 0; s < 8; ++s) {
        int c = tid + s * 256;
        int kc = (c >> 6) & 3, jt = c >> 8;
        srcoff[s] = (jt * 16 + lm) * DIM + kc * 32 + quad * 8;
    }

    for (int jb = 0; jb < NTILES; ++jb) {
        const int jbase = j0 + jb * JTILE;
        __syncthreads();
#pragma unroll
        for (int s = 0; s < 8; ++s)
            sB[tid + s * 256] = *(const bf16x8*)(Fb + (size_t)jbase * DIM + srcoff[s]);
        if (tid < JTILE) {
            sLab[tid] = labels[jbase + tid];
            sX2h[tid] = -0.5f * x2[jbase + tid];
        }
        __syncthreads();

#pragma unroll
        for (int jt = 0; jt < 8; ++jt) {
            const float xjh = sX2h[jt * 16 + lm];
            const int labj = sLab[jt * 16 + lm];
            f32x4 acc0, acc1;
#pragma unroll
            for (int r = 0; r < 4; ++r) {
                acc0[r] = x2ih[r] + xjh;
                acc1[r] = x2ih[4 + r] + xjh;
            }
#pragma unroll
            for (int kc = 0; kc < 4; ++kc) {
                bf16x8 b = sB[(jt * 4 + kc) * 64 + lane];        // lane-linear
                acc0 = __builtin_amdgcn_mfma_f32_16x16x32_bf16(a[0][kc], b, acc0, 0, 0, 0);
                acc1 = __builtin_amdgcn_mfma_f32_16x16x32_bf16(a[1][kc], b, acc1, 0, 0, 0);
            }
#pragma unroll
            for (int g = 0; g < 2; ++g)
#pragma unroll
                for (int r = 0; r < 4; ++r) {
                    const int idx = g * 4 + r;
                    float av = (g == 0) ? acc0[r] : acc1[r];
                    float d2h = fmaxf(-av, 5e-9f);               // d2/2
                    float s = __builtin_amdgcn_sqrtf(d2h);       // dist = sqrt2*s
                    float ne = __expf(-SQRT2_F * s);             // exp(-dist)
                    bool same = (labj == labi[idx]);
                    float mne = same ? 0.f : ne;
                    nl[idx] += mne;
                    ns[idx] = fmaf(mne, s, ns[idx]);
                    if (same) {                                  // rare (~0.2%)
                        float pe = __expf(fmaf(SQRT2_F, s, -30.f));
                        pl[idx] += pe;
                        ps[idx] = fmaf(pe, s, ps[idx]);
                    }
                }
        }
    }

    // reduce over the 16 lm-lanes sharing each i-row
#pragma unroll
    for (int m = 1; m < 16; m <<= 1)
#pragma unroll
        for (int i = 0; i < 8; ++i) {
            nl[i] += __shfl_xor(nl[i], m, 64);
            ns[i] += __shfl_xor(ns[i], m, 64);
            pl[i] += __shfl_xor(pl[i], m, 64);
            ps[i] += __shfl_xor(ps[i], m, 64);
        }
    if (lm == 0) {
#pragma unroll
        for (int g = 0; g < 2; ++g)
#pragma unroll
            for (int r = 0; r < 4; ++r) {
                int row = wbase + g * 16 + quad * 4 + r;
                partial[(size_t)jslice * NROWS + row] =
                    make_float4(pl[g * 4 + r], ps[g * 4 + r], nl[g * 4 + r], ns[g * 4 + r]);
            }
    }

    // -------- last-block finalize (threadfence + device-scope counter) ------
    __threadfence();                         // release: partials -> device
    __syncthreads();
    if (tid == 0) sDone = (atomicAdd(counter, 1) == NBLK - 1);
    __syncthreads();
    if (sDone) {
        __threadfence();                     // acquire: see all blocks' partials
        float sum = 0.f, cnt = 0.f;
        for (int row = tid; row < NROWS; row += 256) {
            float pls = 0.f, pss = 0.f, nls = 0.f, nss = 0.f;
#pragma unroll
            for (int s2 = 0; s2 < JSPLIT; ++s2) {
                float4 p = partial[(size_t)s2 * NROWS + row];
                pls += p.x; pss += p.y; nls += p.z; nss += p.w;
            }
            if (pls > 1e-12f && nls > 0.f) {
                float x = fmaf(SQRT2_F, pss / pls - nss / nls, MARGIN_F);
                sum += fmaxf(x, 0.f) + log1pf(__expf(-fabsf(x)));  // softplus
                cnt += 1.f;
            }
        }
#pragma unroll
        for (int m = 32; m > 0; m >>= 1) {
            sum += __shfl_xor(sum, m, 64);
            cnt += __shfl_xor(cnt, m, 64);
        }
        if (lane == 0) { rS[wave] = sum; rC[wave] = cnt; }
        __syncthreads();
        if (tid == 0)
            out[0] = (rS[0] + rS[1] + rS[2] + rS[3]) /
                     fmaxf(rC[0] + rC[1] + rC[2] + rC[3], 1.0f);
    }
}

// ---------------- launcher ----------------
extern "C" void kernel_launch(void* const* d_in, const int* in_sizes, int n_in,
                              void* d_out, int out_size, void* d_ws, size_t ws_size,
                              hipStream_t stream) {
    const float* F = (const float*)d_in[0];
    const int* labels = (const int*)d_in[1];
    float* out = (float*)d_out;

    char* ws = (char*)d_ws;
    __hip_bfloat16* Fb = (__hip_bfloat16*)ws;                      // 2 MB
    size_t off = (size_t)NROWS * DIM * 2;
    float* x2 = (float*)(ws + off); off += (size_t)NROWS * 4;      // 32 KB
    int* counter = (int*)(ws + off); off += 64;                    // completion counter
    float4* partial = (float4*)(ws + off);                         // 2 MB (JSPLIT=16)

    prep_kernel<<<NROWS / 16, 256, 0, stream>>>(F, Fb, x2, counter);
    pairs_kernel<<<dim3(64, JSPLIT), 256, 0, stream>>>(Fb, x2, labels, partial,
                                                       counter, out);
}

// Round 8
// 328.996 us; speedup vs baseline: 1.1797x; 1.1797x over previous
//
#include <hip/hip_runtime.h>
#include <hip/hip_bf16.h>

// TripletLoss N=8192, D=128. Round 8: 4 dispatches (no fences, no coop).
// prep scales features by C = sqrt2/ln2 before bf16 cast, so with MFMA C-init
// = -(x2i'+x2j')/2 (primes = scaled), u = -acc = d2/ln^2(2). Then
//   sp = sqrt(u) = dist/ln2
//   v_exp2(-sp)          = e^{-dist}        (neg softmax weight)
//   v_exp2(sp - 30/ln2)  = e^{dist-30}      (pos weight, shift-stabilized)
// All dist-weighted sums kept in sp-units; finalize multiplies by ln2.
// x2 is computed from the bf16-ROUNDED scaled values so self-distance == 0.
// Self-pair contributes e^-30 ~ 9.4e-14 to positives; excluded by pl>1e-12.
// LDS B-tile fragment-contiguous ([jt][kc][lane] x 16B): zero bank conflicts
// (verified round 6). 2048 blocks, 16.6 KB LDS, VGPR<=64 -> ~8 blocks/CU.

typedef __bf16 bf16x8 __attribute__((ext_vector_type(8)));
typedef float f32x4 __attribute__((ext_vector_type(4)));

#define NROWS 8192
#define DIM 128
#define MARGIN_F 0.3f
#define LN2_F 0.69314718f
#define SCALE_C 2.0402789f        // sqrt(2)/ln(2)
#define EPS_U 2.0813689e-8f       // 1e-8 / ln^2(2)  (reference clip at 1e-8)
#define POS_SHIFT_L2 43.2808512f  // 30 / ln(2)

// ---------------- dispatch 1: scaled bf16 cast + row norms + zero gstat ----
__global__ __launch_bounds__(256) void prep_kernel(const float* __restrict__ F,
                                                   __hip_bfloat16* __restrict__ Fb,
                                                   float* __restrict__ x2,
                                                   float* __restrict__ gstat) {
    const int tid = threadIdx.x;
    const int row = blockIdx.x * 16 + (tid >> 4);
    const int c8 = tid & 15;                     // 16 threads/row, 8 floats each
    const float4* src = (const float4*)(F + (size_t)row * DIM);
    float4 f0 = src[c8 * 2], f1 = src[c8 * 2 + 1];
    float v[8] = {f0.x, f0.y, f0.z, f0.w, f1.x, f1.y, f1.z, f1.w};
    union { bf16x8 v8; __hip_bfloat16 h[8]; } pk;
    float ss = 0.f;
#pragma unroll
    for (int k = 0; k < 8; ++k) {
        __hip_bfloat16 h = __float2bfloat16(v[k] * SCALE_C);
        pk.h[k] = h;
        float hr = __bfloat162float(h);          // rounded value -> exact self-d2=0
        ss = fmaf(hr, hr, ss);
    }
    *(bf16x8*)(Fb + (size_t)row * DIM + c8 * 8) = pk.v8;
#pragma unroll
    for (int m = 8; m > 0; m >>= 1) ss += __shfl_xor(ss, m, 64);
    if (c8 == 0) x2[row] = ss;
    if (blockIdx.x == 0 && tid < 2) gstat[tid] = 0.f;
}

// ---------------- dispatch 2: fused GEMM + mining ----------------
// grid (64, jsplit); block 256 = 4 waves x 32 i-rows; j swept in 64-wide
// fragment-contiguous LDS tiles. No atomics, no fences.
__global__ __launch_bounds__(256, 8) void pairs_kernel(
        const __hip_bfloat16* __restrict__ Fb,
        const float* __restrict__ x2,
        const int* __restrict__ labels,
        float4* __restrict__ partial,
        int ntiles, int jspan) {
    __shared__ bf16x8 sB[1024];          // 16 KB; chunk c = (jt*4+kc)*64 + lane
    __shared__ int sLab[64];
    __shared__ float sX2h[64];           // -0.5 * x2j'

    const int tid = threadIdx.x;
    const int wave = tid >> 6, lane = tid & 63;
    const int quad = lane >> 4, lm = lane & 15;
    const int wbase = blockIdx.x * 128 + wave * 32;   // this wave's 32 i-rows
    const int j0 = blockIdx.y * jspan;

    // A fragments: 2 row-groups x 4 K-chunks; A[m=lm][k=quad*8+j]
    bf16x8 a[2][4];
#pragma unroll
    for (int g = 0; g < 2; ++g)
#pragma unroll
        for (int kc = 0; kc < 4; ++kc)
            a[g][kc] = *(const bf16x8*)(Fb + (size_t)(wbase + g * 16 + lm) * DIM
                                        + kc * 32 + quad * 8);

    // C/D: col(n)=lm (j), row(m)=quad*4+r (i); idx = g*4+r
    float x2ih[8]; int labi[8];
#pragma unroll
    for (int g = 0; g < 2; ++g)
#pragma unroll
        for (int r = 0; r < 4; ++r) {
            int row = wbase + g * 16 + quad * 4 + r;
            x2ih[g * 4 + r] = -0.5f * x2[row];
            labi[g * 4 + r] = labels[row];
        }

    float nl[8], ns[8], pl[8], ps[8];
#pragma unroll
    for (int i = 0; i < 8; ++i) { nl[i] = 0.f; ns[i] = 0.f; pl[i] = 0.f; ps[i] = 0.f; }

    // staging map: chunk c = tid + s*256; jt=c>>8, kc=(c>>6)&3; lane bits const
    int srcoff[4];
#pragma unroll
    for (int s = 0; s < 4; ++s) {
        int c = tid + s * 256;
        int kc = (c >> 6) & 3, jt = c >> 8;
        srcoff[s] = (jt * 16 + lm) * DIM + kc * 32 + quad * 8;
    }

    for (int jb = 0; jb < ntiles; ++jb) {
        const int jbase = j0 + jb * 64;
        __syncthreads();
#pragma unroll
        for (int s = 0; s < 4; ++s)
            sB[tid + s * 256] = *(const bf16x8*)(Fb + (size_t)jbase * DIM + srcoff[s]);
        if (tid < 64) {
            sLab[tid] = labels[jbase + tid];
            sX2h[tid] = -0.5f * x2[jbase + tid];
        }
        __syncthreads();

#pragma unroll
        for (int jt = 0; jt < 4; ++jt) {
            const float xjh = sX2h[jt * 16 + lm];
            const int labj = sLab[jt * 16 + lm];
            f32x4 acc0, acc1;
#pragma unroll
            for (int r = 0; r < 4; ++r) {
                acc0[r] = x2ih[r] + xjh;
                acc1[r] = x2ih[4 + r] + xjh;
            }
#pragma unroll
            for (int kc = 0; kc < 4; ++kc) {
                bf16x8 b = sB[(jt * 4 + kc) * 64 + lane];        // lane-linear
                acc0 = __builtin_amdgcn_mfma_f32_16x16x32_bf16(a[0][kc], b, acc0, 0, 0, 0);
                acc1 = __builtin_amdgcn_mfma_f32_16x16x32_bf16(a[1][kc], b, acc1, 0, 0, 0);
            }
#pragma unroll
            for (int g = 0; g < 2; ++g)
#pragma unroll
                for (int r = 0; r < 4; ++r) {
                    const int idx = g * 4 + r;
                    float av = (g == 0) ? acc0[r] : acc1[r];
                    float u = fmaxf(-av, EPS_U);                 // d2/ln^2(2)
                    float sp = __builtin_amdgcn_sqrtf(u);        // dist/ln2
                    float ne = __builtin_amdgcn_exp2f(-sp);      // e^{-dist}
                    bool same = (labj == labi[idx]);
                    float mne = same ? 0.f : ne;
                    nl[idx] += mne;
                    ns[idx] = fmaf(mne, sp, ns[idx]);
                    if (same) {                                  // rare (~0.2%)
                        float pe = __builtin_amdgcn_exp2f(sp - POS_SHIFT_L2);
                        pl[idx] += pe;
                        ps[idx] = fmaf(pe, sp, ps[idx]);
                    }
                }
        }
    }

    // reduce over the 16 lm-lanes sharing each i-row
#pragma unroll
    for (int m = 1; m < 16; m <<= 1)
#pragma unroll
        for (int i = 0; i < 8; ++i) {
            nl[i] += __shfl_xor(nl[i], m, 64);
            ns[i] += __shfl_xor(ns[i], m, 64);
            pl[i] += __shfl_xor(pl[i], m, 64);
            ps[i] += __shfl_xor(ps[i], m, 64);
        }
    if (lm == 0) {
#pragma unroll
        for (int g = 0; g < 2; ++g)
#pragma unroll
            for (int r = 0; r < 4; ++r) {
                int row = wbase + g * 16 + quad * 4 + r;
                partial[(size_t)blockIdx.y * NROWS + row] =
                    make_float4(pl[g * 4 + r], ps[g * 4 + r], nl[g * 4 + r], ns[g * 4 + r]);
            }
    }
}

// ---------------- dispatch 3: per-row loss, multi-block reduce -------------
__global__ __launch_bounds__(256) void finalize_kernel(const float4* __restrict__ partial,
                                                       float* __restrict__ gstat,
                                                       int jsplit) {
    const int row = blockIdx.x * 256 + threadIdx.x;
    float pls = 0.f, pss = 0.f, nls = 0.f, nss = 0.f;
    for (int s = 0; s < jsplit; ++s) {
        float4 p = partial[(size_t)s * NROWS + row];
        pls += p.x; pss += p.y; nls += p.z; nss += p.w;
    }
    float sum = 0.f, cnt = 0.f;
    if (pls > 1e-12f && nls > 0.f) {     // 1e-12 excludes self-only (e^-30)
        float x = fmaf(LN2_F, pss / pls - nss / nls, MARGIN_F);
        sum = fmaxf(x, 0.f) + log1pf(__expf(-fabsf(x)));   // stable softplus
        cnt = 1.f;
    }
#pragma unroll
    for (int m = 32; m > 0; m >>= 1) {
        sum += __shfl_xor(sum, m, 64);
        cnt += __shfl_xor(cnt, m, 64);
    }
    __shared__ float sS[4], sC[4];
    const int wave = threadIdx.x >> 6, lane = threadIdx.x & 63;
    if (lane == 0) { sS[wave] = sum; sC[wave] = cnt; }
    __syncthreads();
    if (threadIdx.x == 0) {
        unsafeAtomicAdd(&gstat[0], sS[0] + sS[1] + sS[2] + sS[3]);
        unsafeAtomicAdd(&gstat[1], sC[0] + sC[1] + sC[2] + sC[3]);
    }
}

__global__ void div_kernel(const float* __restrict__ gstat, float* __restrict__ out) {
    out[0] = gstat[0] / fmaxf(gstat[1], 1.0f);
}

// ---------------- launcher ----------------
extern "C" void kernel_launch(void* const* d_in, const int* in_sizes, int n_in,
                              void* d_out, int out_size, void* d_ws, size_t ws_size,
                              hipStream_t stream) {
    const float* F = (const float*)d_in[0];
    const int* labels = (const int*)d_in[1];
    float* out = (float*)d_out;

    char* ws = (char*)d_ws;
    __hip_bfloat16* Fb = (__hip_bfloat16*)ws;                      // 2 MB
    size_t off = (size_t)NROWS * DIM * 2;
    float* x2 = (float*)(ws + off); off += (size_t)NROWS * 4;      // 32 KB
    float* gstat = (float*)(ws + off); off += 64;
    float4* partial = (float4*)(ws + off);

    // largest j-split whose partial array fits the workspace (32 -> 4 MB)
    int jsplit = 32;
    while (jsplit > 1 && off + (size_t)jsplit * NROWS * 16 > ws_size) jsplit >>= 1;
    const int jspan = NROWS / jsplit;
    const int ntiles = jspan / 64;

    prep_kernel<<<NROWS / 16, 256, 0, stream>>>(F, Fb, x2, gstat);
    pairs_kernel<<<dim3(64, jsplit), 256, 0, stream>>>(Fb, x2, labels, partial,
                                                       ntiles, jspan);
    finalize_kernel<<<NROWS / 256, 256, 0, stream>>>(partial, gstat, jsplit);
    div_kernel<<<1, 1, 0, stream>>>(gstat, out);
}

// Round 9
// 125.485 us; speedup vs baseline: 3.0929x; 2.6218x over previous
//
#include <hip/hip_runtime.h>
#include <hip/hip_bf16.h>

// TripletLoss N=8192, D=128. Round 9: round-8 structure with the register
// allocator UNCLAMPED (launch_bounds (256,4) -> compiler's natural 64 VGPR;
// round 8's (256,8) forced 32 VGPR and spilled accumulators to scratch,
// generating 1.18 GB of HBM traffic).
// Math: prep scales features by C = sqrt2/ln2 before bf16 cast; MFMA C-init
// = -(x2i'+x2j')/2 so u = -acc = d2/ln^2(2);
//   sp = sqrt(u) = dist/ln2
//   v_exp2(-sp)          = e^{-dist}      (neg weight)
//   v_exp2(sp - 30/ln2)  = e^{dist-30}    (pos weight, shift-stabilized)
// Sums kept in sp-units; finalize multiplies by ln2. x2 from bf16-ROUNDED
// values so self-distance == 0; self contributes e^-30 ~ 9.4e-14 to
// positives, excluded by pl > 1e-12. LDS B-tile fragment-contiguous
// ([jt][kc][lane] x 16B): zero bank conflicts (verified rounds 6-8).

typedef __bf16 bf16x8 __attribute__((ext_vector_type(8)));
typedef float f32x4 __attribute__((ext_vector_type(4)));

#define NROWS 8192
#define DIM 128
#define MARGIN_F 0.3f
#define LN2_F 0.69314718f
#define SCALE_C 2.0402789f        // sqrt(2)/ln(2)
#define EPS_U 2.0813689e-8f       // 1e-8 / ln^2(2)
#define POS_SHIFT_L2 43.2808512f  // 30 / ln(2)

// ---------------- dispatch 1: scaled bf16 cast + row norms + zero gstat ----
__global__ __launch_bounds__(256) void prep_kernel(const float* __restrict__ F,
                                                   __hip_bfloat16* __restrict__ Fb,
                                                   float* __restrict__ x2,
                                                   float* __restrict__ gstat) {
    const int tid = threadIdx.x;
    const int row = blockIdx.x * 16 + (tid >> 4);
    const int c8 = tid & 15;                     // 16 threads/row, 8 floats each
    const float4* src = (const float4*)(F + (size_t)row * DIM);
    float4 f0 = src[c8 * 2], f1 = src[c8 * 2 + 1];
    float v[8] = {f0.x, f0.y, f0.z, f0.w, f1.x, f1.y, f1.z, f1.w};
    union { bf16x8 v8; __hip_bfloat16 h[8]; } pk;
    float ss = 0.f;
#pragma unroll
    for (int k = 0; k < 8; ++k) {
        __hip_bfloat16 h = __float2bfloat16(v[k] * SCALE_C);
        pk.h[k] = h;
        float hr = __bfloat162float(h);          // rounded -> exact self-d2 = 0
        ss = fmaf(hr, hr, ss);
    }
    *(bf16x8*)(Fb + (size_t)row * DIM + c8 * 8) = pk.v8;
#pragma unroll
    for (int m = 8; m > 0; m >>= 1) ss += __shfl_xor(ss, m, 64);
    if (c8 == 0) x2[row] = ss;
    if (blockIdx.x == 0 && tid < 2) gstat[tid] = 0.f;
}

// ---------------- dispatch 2: fused GEMM + mining ----------------
// grid (64, jsplit); block 256 = 4 waves x 32 i-rows; j swept in 64-wide
// fragment-contiguous LDS tiles. No atomics, no fences.
// launch_bounds (256,4): VGPR cap 128; natural usage 64 -> 8 waves/EU by HW.
__global__ __launch_bounds__(256, 4) void pairs_kernel(
        const __hip_bfloat16* __restrict__ Fb,
        const float* __restrict__ x2,
        const int* __restrict__ labels,
        float4* __restrict__ partial,
        int ntiles, int jspan) {
    __shared__ bf16x8 sB[1024];          // 16 KB; chunk c = (jt*4+kc)*64 + lane
    __shared__ int sLab[64];
    __shared__ float sX2h[64];           // -0.5 * x2j'

    const int tid = threadIdx.x;
    const int wave = tid >> 6, lane = tid & 63;
    const int quad = lane >> 4, lm = lane & 15;
    const int wbase = blockIdx.x * 128 + wave * 32;   // this wave's 32 i-rows
    const int j0 = blockIdx.y * jspan;

    // A fragments: 2 row-groups x 4 K-chunks; A[m=lm][k=quad*8+j]
    bf16x8 a[2][4];
#pragma unroll
    for (int g = 0; g < 2; ++g)
#pragma unroll
        for (int kc = 0; kc < 4; ++kc)
            a[g][kc] = *(const bf16x8*)(Fb + (size_t)(wbase + g * 16 + lm) * DIM
                                        + kc * 32 + quad * 8);

    // C/D: col(n)=lm (j), row(m)=quad*4+r (i); idx = g*4+r
    float x2ih[8]; int labi[8];
#pragma unroll
    for (int g = 0; g < 2; ++g)
#pragma unroll
        for (int r = 0; r < 4; ++r) {
            int row = wbase + g * 16 + quad * 4 + r;
            x2ih[g * 4 + r] = -0.5f * x2[row];
            labi[g * 4 + r] = labels[row];
        }

    float nl[8], ns[8], pl[8], ps[8];
#pragma unroll
    for (int i = 0; i < 8; ++i) { nl[i] = 0.f; ns[i] = 0.f; pl[i] = 0.f; ps[i] = 0.f; }

    // staging map: chunk c = tid + s*256; jt=c>>8, kc=(c>>6)&3; lane bits const
    int srcoff[4];
#pragma unroll
    for (int s = 0; s < 4; ++s) {
        int c = tid + s * 256;
        int kc = (c >> 6) & 3, jt = c >> 8;
        srcoff[s] = (jt * 16 + lm) * DIM + kc * 32 + quad * 8;
    }

    for (int jb = 0; jb < ntiles; ++jb) {
        const int jbase = j0 + jb * 64;
        __syncthreads();
#pragma unroll
        for (int s = 0; s < 4; ++s)
            sB[tid + s * 256] = *(const bf16x8*)(Fb + (size_t)jbase * DIM + srcoff[s]);
        if (tid < 64) {
            sLab[tid] = labels[jbase + tid];
            sX2h[tid] = -0.5f * x2[jbase + tid];
        }
        __syncthreads();

#pragma unroll
        for (int jt = 0; jt < 4; ++jt) {
            const float xjh = sX2h[jt * 16 + lm];
            const int labj = sLab[jt * 16 + lm];
            f32x4 acc0, acc1;
#pragma unroll
            for (int r = 0; r < 4; ++r) {
                acc0[r] = x2ih[r] + xjh;
                acc1[r] = x2ih[4 + r] + xjh;
            }
#pragma unroll
            for (int kc = 0; kc < 4; ++kc) {
                bf16x8 b = sB[(jt * 4 + kc) * 64 + lane];        // lane-linear
                acc0 = __builtin_amdgcn_mfma_f32_16x16x32_bf16(a[0][kc], b, acc0, 0, 0, 0);
                acc1 = __builtin_amdgcn_mfma_f32_16x16x32_bf16(a[1][kc], b, acc1, 0, 0, 0);
            }
#pragma unroll
            for (int g = 0; g < 2; ++g)
#pragma unroll
                for (int r = 0; r < 4; ++r) {
                    const int idx = g * 4 + r;
                    float av = (g == 0) ? acc0[r] : acc1[r];
                    float u = fmaxf(-av, EPS_U);                 // d2/ln^2(2)
                    float sp = __builtin_amdgcn_sqrtf(u);        // dist/ln2
                    float ne = __builtin_amdgcn_exp2f(-sp);      // e^{-dist}
                    bool same = (labj == labi[idx]);
                    float mne = same ? 0.f : ne;
                    nl[idx] += mne;
                    ns[idx] = fmaf(mne, sp, ns[idx]);
                    if (same) {                                  // rare (~0.2%)
                        float pe = __builtin_amdgcn_exp2f(sp - POS_SHIFT_L2);
                        pl[idx] += pe;
                        ps[idx] = fmaf(pe, sp, ps[idx]);
                    }
                }
        }
    }

    // reduce over the 16 lm-lanes sharing each i-row
#pragma unroll
    for (int m = 1; m < 16; m <<= 1)
#pragma unroll
        for (int i = 0; i < 8; ++i) {
            nl[i] += __shfl_xor(nl[i], m, 64);
            ns[i] += __shfl_xor(ns[i], m, 64);
            pl[i] += __shfl_xor(pl[i], m, 64);
            ps[i] += __shfl_xor(ps[i], m, 64);
        }
    if (lm == 0) {
#pragma unroll
        for (int g = 0; g < 2; ++g)
#pragma unroll
            for (int r = 0; r < 4; ++r) {
                int row = wbase + g * 16 + quad * 4 + r;
                partial[(size_t)blockIdx.y * NROWS + row] =
                    make_float4(pl[g * 4 + r], ps[g * 4 + r], nl[g * 4 + r], ns[g * 4 + r]);
            }
    }
}

// ---------------- dispatch 3: per-row loss, multi-block reduce -------------
__global__ __launch_bounds__(256) void finalize_kernel(const float4* __restrict__ partial,
                                                       float* __restrict__ gstat,
                                                       int jsplit) {
    const int row = blockIdx.x * 256 + threadIdx.x;
    float pls = 0.f, pss = 0.f, nls = 0.f, nss = 0.f;
    for (int s = 0; s < jsplit; ++s) {
        float4 p = partial[(size_t)s * NROWS + row];
        pls += p.x; pss += p.y; nls += p.z; nss += p.w;
    }
    float sum = 0.f, cnt = 0.f;
    if (pls > 1e-12f && nls > 0.f) {     // 1e-12 excludes self-only (e^-30)
        float x = fmaf(LN2_F, pss / pls - nss / nls, MARGIN_F);
        sum = fmaxf(x, 0.f) + log1pf(__expf(-fabsf(x)));   // stable softplus
        cnt = 1.f;
    }
#pragma unroll
    for (int m = 32; m > 0; m >>= 1) {
        sum += __shfl_xor(sum, m, 64);
        cnt += __shfl_xor(cnt, m, 64);
    }
    __shared__ float sS[4], sC[4];
    const int wave = threadIdx.x >> 6, lane = threadIdx.x & 63;
    if (lane == 0) { sS[wave] = sum; sC[wave] = cnt; }
    __syncthreads();
    if (threadIdx.x == 0) {
        unsafeAtomicAdd(&gstat[0], sS[0] + sS[1] + sS[2] + sS[3]);
        unsafeAtomicAdd(&gstat[1], sC[0] + sC[1] + sC[2] + sC[3]);
    }
}

__global__ void div_kernel(const float* __restrict__ gstat, float* __restrict__ out) {
    out[0] = gstat[0] / fmaxf(gstat[1], 1.0f);
}

// ---------------- launcher ----------------
extern "C" void kernel_launch(void* const* d_in, const int* in_sizes, int n_in,
                              void* d_out, int out_size, void* d_ws, size_t ws_size,
                              hipStream_t stream) {
    const float* F = (const float*)d_in[0];
    const int* labels = (const int*)d_in[1];
    float* out = (float*)d_out;

    char* ws = (char*)d_ws;
    __hip_bfloat16* Fb = (__hip_bfloat16*)ws;                      // 2 MB
    size_t off = (size_t)NROWS * DIM * 2;
    float* x2 = (float*)(ws + off); off += (size_t)NROWS * 4;      // 32 KB
    float* gstat = (float*)(ws + off); off += 64;
    float4* partial = (float4*)(ws + off);

    // largest j-split whose partial array fits the workspace (32 -> 4 MB)
    int jsplit = 32;
    while (jsplit > 1 && off + (size_t)jsplit * NROWS * 16 > ws_size) jsplit >>= 1;
    const int jspan = NROWS / jsplit;
    const int ntiles = jspan / 64;

    prep_kernel<<<NROWS / 16, 256, 0, stream>>>(F, Fb, x2, gstat);
    pairs_kernel<<<dim3(64, jsplit), 256, 0, stream>>>(Fb, x2, labels, partial,
                                                       ntiles, jspan);
    finalize_kernel<<<NROWS / 256, 256, 0, stream>>>(partial, gstat, jsplit);
    div_kernel<<<1, 1, 0, stream>>>(gstat, out);
}